// Round 19
// baseline (147.641 us; speedup 1.0000x reference)
//
#include <hip/hip_runtime.h>
#include <cstddef>

// EdgeDegreeEmbedding fused pipeline for MI355X (gfx950)
//
//   h1 = silu(LN(x_edge @ w1 + b1))          [E,64]
//   h2 = silu(LN(h1 @ w2 + b2))              [E,64]
//   m0 = (h2 @ w3 + b3) * env(d/12)/5        -> m0p perm-K-major bf16
//   out[dst[e]] += W-contraction              (per-node MFMA GEMM, K=5*cnt)
//   out initialized to x.
//
// Round-19: wigner compaction merged INTO the mlp chunk loop as a phase
// (same code path for every block — avoids r16's divergent-role regalloc
// failure). Per 16-edge chunk: assign ipos (atomicAdd) -> stream the 16
// wigner matrices through a 20KB LDS buffer (two 8-edge halves, coalesced
// float4) emitting wkT -> run the MFMA/LN phases. Staging registers are
// phase-local (no r8-style cross-phase spill). Overlap comes from 500
// co-resident blocks drifting across phases. compact kernel + ipos array
// eliminated.

constexpr int C_DIM   = 128;
constexpr int NCOEF   = 25;
constexpr int M0d     = 5;
constexpr int MCH     = 5;     // 16-edge chunks per mlp block
constexpr float EPS_LN      = 1e-5f;
constexpr float INV_CUTOFF  = 1.0f / 12.0f;
constexpr float INV_RESCALE = 0.2f;

typedef __attribute__((ext_vector_type(8))) short short8;   // 8 bf16
typedef __attribute__((ext_vector_type(4))) short short4v;  // 4 bf16
typedef __attribute__((ext_vector_type(4))) float f32x4;

__device__ __forceinline__ short f2bf(float f) {
    unsigned u = __float_as_uint(f);
    unsigned r = u + 0x7FFFu + ((u >> 16) & 1u);   // round-to-nearest-even
    return (short)(r >> 16);
}

__device__ __forceinline__ float silu(float z) {
    return z / (1.0f + __expf(-z));
}

// -------- Kernel P: zero bins + weights -> bf16 transposed (one launch) -------
__global__ __launch_bounds__(256) void prep_kernel(
    const float* __restrict__ w1, const float* __restrict__ w2,
    const float* __restrict__ w3,
    short* __restrict__ w1T, short* __restrict__ w2T, short* __restrict__ w3T,
    int* __restrict__ cnt, int n2)
{
    int i = blockIdx.x * 256 + threadIdx.x;
    if (i < n2) cnt[i] = 0;
    if (i < 64 * 128) {             // w1T[n*128+k] = w1[k*64+n]
        int n = i >> 7, k = i & 127;
        w1T[i] = f2bf(w1[k * 64 + n]);
    }
    if (i < 64 * 64) {              // w2T[n*64+k] = w2[k*64+n]
        int n = i >> 6, k = i & 63;
        w2T[i] = f2bf(w2[k * 64 + n]);
    }
    if (i < 640 * 64) {             // w3T[n*64+k] = w3[k*640+n]
        int n = i >> 6, k = i & 63;
        w3T[i] = f2bf(w3[k * 640 + n]);
    }
}

// ---------------- Binning ----------------
__global__ __launch_bounds__(256) void count_kernel(
    const int* __restrict__ edge_index, const int* __restrict__ noff,
    int* __restrict__ cnt, int E, int N)
{
    int e = blockIdx.x * 256 + threadIdx.x;
    if (e < E) {
        int d = edge_index[E + e] - noff[0];
        if (d >= 0 && d < N) atomicAdd(&cnt[d], 1);
    }
}

__global__ __launch_bounds__(256) void scan_kernel(
    const int* __restrict__ cnt, int* __restrict__ offs, int N)
{
    __shared__ int s_wsum[4];
    const int t = threadIdx.x;
    const int lane = t & 63, w = t >> 6;
    const int chunk = (N + 255) / 256;
    const int base = t * chunk;

    int s = 0;
    for (int j = 0; j < chunk; ++j)
        if (base + j < N) s += cnt[base + j];

    int v = s;
    #pragma unroll
    for (int off = 1; off < 64; off <<= 1) {
        int u = __shfl_up(v, off, 64);
        if (lane >= off) v += u;
    }
    if (lane == 63) s_wsum[w] = v;
    __syncthreads();
    int wbase = 0;
    for (int k = 0; k < w; ++k) wbase += s_wsum[k];
    int run = wbase + v - s;

    if (t == 0) offs[0] = 0;
    for (int j = 0; j < chunk; ++j) {
        if (base + j < N) {
            run += cnt[base + j];
            offs[base + j + 1] = run;
        }
    }
}

// ------- Kernel A: MFMA radial MLP (persistent weights) + wigner compact ------
// Each block: MCH chunks of 16 edges. Per chunk: (1) assign ipos via
// atomicAdd; (2) stream the chunk's wigner matrices through a 20KB LDS
// buffer in two 8-edge halves, emit wkT K-major rows; (3) MFMA MLP with
// persistent weights -> m0p perm-K-major stores.
__global__ __launch_bounds__(256, 2) void mlp_mfma_kernel(
    const float* __restrict__ x_edge,        // [E,128]
    const float* __restrict__ edge_distance, // [E]
    const float* __restrict__ wigner_inv,    // [E,625]
    const int*   __restrict__ edge_index,    // [2,E]
    const int*   __restrict__ noff,
    const int*   __restrict__ offs,          // [N+1]
    int*         __restrict__ cur,           // [N]
    const short* __restrict__ w1T,           // [64][128] bf16
    const float* __restrict__ b1,
    const float* __restrict__ g1, const float* __restrict__ be1,
    const short* __restrict__ w2T,           // [64][64] bf16
    const float* __restrict__ b2,
    const float* __restrict__ g2, const float* __restrict__ be2,
    const short* __restrict__ w3T,           // [640][64] bf16
    const float* __restrict__ b3,
    unsigned short* __restrict__ m0p,        // [(5E+pad)][128] bf16, perm order
    unsigned short* __restrict__ wkT,        // [(5E+pad)][32] bf16, perm order
    int E, int N, int nChunk)
{
    __shared__ __align__(16) float s_wig[8 * 625];   // 20 KB (wigner half)
    __shared__ float s_part[128];                    // LN partials
    __shared__ short sh1[1024];                      // 16x64 bf16, swizzled
    __shared__ short sh2[1024];
    __shared__ int   s_ip[16];

    const int t   = threadIdx.x;
    const int w   = t >> 6;
    const int l   = t & 63;
    const int e16 = l & 15;
    const int g   = l >> 4;
    const int swz = (e16 & 7) << 4;

    char* sh1b = (char*)sh1;
    char* sh2b = (char*)sh2;

    // ---- persistent weights & biases (loaded once per block) ----
    short8 aw1[4], aw2[2], aw3a[10], aw3b[10];
    #pragma unroll
    for (int kt = 0; kt < 4; ++kt)
        aw1[kt] = *(const short8*)(w1T + (w * 16 + e16) * 128 + kt * 32 + 8 * g);
    #pragma unroll
    for (int kt = 0; kt < 2; ++kt)
        aw2[kt] = *(const short8*)(w2T + (w * 16 + e16) * 64 + kt * 32 + 8 * g);
    #pragma unroll
    for (int j = 0; j < 10; ++j) {
        const int nt = w * 10 + j;
        aw3a[j] = *(const short8*)(w3T + (nt * 16 + e16) * 64 + 8 * g);
        aw3b[j] = *(const short8*)(w3T + (nt * 16 + e16) * 64 + 32 + 8 * g);
    }
    const float4 b1v  = *(const float4*)(b1  + w * 16 + 4 * g);
    const float4 g1v  = *(const float4*)(g1  + w * 16 + 4 * g);
    const float4 be1v = *(const float4*)(be1 + w * 16 + 4 * g);
    const float4 b2v  = *(const float4*)(b2  + w * 16 + 4 * g);
    const float4 g2v  = *(const float4*)(g2  + w * 16 + 4 * g);
    const float4 be2v = *(const float4*)(be2 + w * 16 + 4 * g);
    float4 b3v[10];
    #pragma unroll
    for (int j = 0; j < 10; ++j)
        b3v[j] = *(const float4*)(b3 + (w * 10 + j) * 16 + 4 * g);

    const int ch0 = (int)blockIdx.x * MCH;
    const int chE = (ch0 + MCH < nChunk) ? (ch0 + MCH) : nChunk;

    for (int ch = ch0; ch < chE; ++ch) {
        const int g0  = ch * 16;
        const int row = g0 + e16;
        const int rowc = row < E ? row : (E - 1);
        const bool valid = row < E;

        // ---- (1) assign ipos for this chunk's edges ----
        if (t < 16) {
            const int e = g0 + t;
            int ip = -1;
            if (e < E) {
                const int d = edge_index[E + e] - noff[0];
                if (d >= 0 && d < N) {
                    int p = atomicAdd(&cur[d], 1);
                    ip = offs[d] + p;
                }
            }
            s_ip[t] = ip;
        }
        __syncthreads();                                  // s_ip ready; s_wig free

        // ---- (2) wigner compact: two 8-edge halves through s_wig ----
        #pragma unroll
        for (int h = 0; h < 2; ++h) {
            const int e0 = g0 + 8 * h;
            const int nh = (E - e0) < 8 ? ((E - e0) < 0 ? 0 : (E - e0)) : 8;
            if (nh == 8) {
                const float4* src = (const float4*)(wigner_inv + (size_t)e0 * 625);
                #pragma unroll 5
                for (int f = t; f < 1250; f += 256)
                    ((float4*)s_wig)[f] = src[f];
            } else if (nh > 0) {
                const float* src = wigner_inv + (size_t)e0 * 625;
                for (int f = t; f < nh * 625; f += 256)
                    s_wig[f] = src[f];
            }
            __syncthreads();                              // staged
            if (nh > 0) {
                const int total = nh * 160;               // 5 a * 32 i per edge
                #pragma unroll 2
                for (int f = t; f < total; f += 256) {
                    const int el = f / 160;
                    const int r  = f - el * 160;
                    const int a  = r >> 5;
                    const int i  = r & 31;
                    const int ip = s_ip[8 * h + el];
                    if ((unsigned)ip < (unsigned)E) {
                        unsigned short v = 0;
                        if (i < 25) v = (unsigned short)f2bf(s_wig[el * 625 + i * 25 + a * (a + 1)]);
                        wkT[((size_t)ip * 5 + a) * 32 + i] = v;
                    }
                }
            }
            __syncthreads();                              // emit done; buffer reusable
        }

        // ---- (3) MLP for this chunk ----
        float sc;
        {
            float d  = edge_distance[rowc] * INV_CUTOFF;
            float d2 = d * d;
            float d5 = d2 * d2 * d;
            float env = 1.0f + d5 * (-21.0f + d * (35.0f + d * (-15.0f)));
            sc = ((d < 1.0f) ? env : 0.0f) * INV_RESCALE;
        }
        const int ip = valid ? s_ip[e16] : -1;
        const bool ipok = valid && ((unsigned)ip < (unsigned)E);

        // B1 fragments from x_edge
        short8 bx[4];
        {
            const float* xr = x_edge + (size_t)rowc * C_DIM + 8 * g;
            #pragma unroll
            for (int kt = 0; kt < 4; ++kt) {
                float4 f0 = *(const float4*)(xr + kt * 32);
                float4 f1 = *(const float4*)(xr + kt * 32 + 4);
                short8 v;
                v[0] = f2bf(f0.x); v[1] = f2bf(f0.y); v[2] = f2bf(f0.z); v[3] = f2bf(f0.w);
                v[4] = f2bf(f1.x); v[5] = f2bf(f1.y); v[6] = f2bf(f1.z); v[7] = f2bf(f1.w);
                bx[kt] = v;
            }
        }

        // Layer 1
        f32x4 acc1 = {b1v.x, b1v.y, b1v.z, b1v.w};
        #pragma unroll
        for (int kt = 0; kt < 4; ++kt)
            acc1 = __builtin_amdgcn_mfma_f32_16x16x32_bf16(aw1[kt], bx[kt], acc1, 0, 0, 0);

        // LN1 (single-barrier: sum + sumsq) + SiLU -> sh1
        {
            float s = acc1[0] + acc1[1] + acc1[2] + acc1[3];
            float qq = acc1[0]*acc1[0] + acc1[1]*acc1[1] + acc1[2]*acc1[2] + acc1[3]*acc1[3];
            s  += __shfl_xor(s, 16);  s  += __shfl_xor(s, 32);
            qq += __shfl_xor(qq, 16); qq += __shfl_xor(qq, 32);
            if (g == 0) { s_part[w * 16 + e16] = s; s_part[64 + w * 16 + e16] = qq; }
            __syncthreads();
            float mu  = (s_part[e16] + s_part[16 + e16] + s_part[32 + e16] + s_part[48 + e16])
                        * (1.0f / 64.0f);
            float ex2 = (s_part[64 + e16] + s_part[80 + e16] + s_part[96 + e16] + s_part[112 + e16])
                        * (1.0f / 64.0f);
            float var = ex2 - mu * mu;
            float rstd = rsqrtf((var > 0.0f ? var : 0.0f) + EPS_LN);
            short4v hv;
            hv[0] = f2bf(silu((acc1[0] - mu) * rstd * g1v.x + be1v.x));
            hv[1] = f2bf(silu((acc1[1] - mu) * rstd * g1v.y + be1v.y));
            hv[2] = f2bf(silu((acc1[2] - mu) * rstd * g1v.z + be1v.z));
            hv[3] = f2bf(silu((acc1[3] - mu) * rstd * g1v.w + be1v.w));
            __syncthreads();
            *(short4v*)(sh1b + e16 * 128 + ((w * 32 + 8 * g) ^ swz)) = hv;
            __syncthreads();
        }

        // Layer 2
        f32x4 acc2 = {b2v.x, b2v.y, b2v.z, b2v.w};
        {
            short8 bh[2];
            #pragma unroll
            for (int kt = 0; kt < 2; ++kt)
                bh[kt] = *(const short8*)(sh1b + e16 * 128 + ((kt * 64 + 16 * g) ^ swz));
            #pragma unroll
            for (int kt = 0; kt < 2; ++kt)
                acc2 = __builtin_amdgcn_mfma_f32_16x16x32_bf16(aw2[kt], bh[kt], acc2, 0, 0, 0);
        }

        // LN2 (single-barrier) + SiLU -> sh2
        {
            float s = acc2[0] + acc2[1] + acc2[2] + acc2[3];
            float qq = acc2[0]*acc2[0] + acc2[1]*acc2[1] + acc2[2]*acc2[2] + acc2[3]*acc2[3];
            s  += __shfl_xor(s, 16);  s  += __shfl_xor(s, 32);
            qq += __shfl_xor(qq, 16); qq += __shfl_xor(qq, 32);
            if (g == 0) { s_part[w * 16 + e16] = s; s_part[64 + w * 16 + e16] = qq; }
            __syncthreads();
            float mu  = (s_part[e16] + s_part[16 + e16] + s_part[32 + e16] + s_part[48 + e16])
                        * (1.0f / 64.0f);
            float ex2 = (s_part[64 + e16] + s_part[80 + e16] + s_part[96 + e16] + s_part[112 + e16])
                        * (1.0f / 64.0f);
            float var = ex2 - mu * mu;
            float rstd = rsqrtf((var > 0.0f ? var : 0.0f) + EPS_LN);
            short4v hv;
            hv[0] = f2bf(silu((acc2[0] - mu) * rstd * g2v.x + be2v.x));
            hv[1] = f2bf(silu((acc2[1] - mu) * rstd * g2v.y + be2v.y));
            hv[2] = f2bf(silu((acc2[2] - mu) * rstd * g2v.z + be2v.z));
            hv[3] = f2bf(silu((acc2[3] - mu) * rstd * g2v.w + be2v.w));
            __syncthreads();
            *(short4v*)(sh2b + e16 * 128 + ((w * 32 + 8 * g) ^ swz)) = hv;
            __syncthreads();
        }

        // Layer 3: 10 tiles/wave from persistent regs, perm-ordered stores
        {
            short8 bh2[2];
            #pragma unroll
            for (int kt = 0; kt < 2; ++kt)
                bh2[kt] = *(const short8*)(sh2b + e16 * 128 + ((kt * 64 + 16 * g) ^ swz));

            #pragma unroll
            for (int j = 0; j < 10; ++j) {
                const int nt = w * 10 + j;
                f32x4 a3 = {b3v[j].x, b3v[j].y, b3v[j].z, b3v[j].w};
                a3 = __builtin_amdgcn_mfma_f32_16x16x32_bf16(aw3a[j], bh2[0], a3, 0, 0, 0);
                a3 = __builtin_amdgcn_mfma_f32_16x16x32_bf16(aw3b[j], bh2[1], a3, 0, 0, 0);
                if (ipok) {
                    short4v o;
                    o[0] = f2bf(a3[0] * sc);
                    o[1] = f2bf(a3[1] * sc);
                    o[2] = f2bf(a3[2] * sc);
                    o[3] = f2bf(a3[3] * sc);
                    *(short4v*)(m0p + ((size_t)ip * 5 + (nt >> 3)) * 128
                                    + ((nt & 7) << 4) + 4 * g) = o;
                }
            }
        }
        __syncthreads();   // protect LDS reuse across chunks
    }
}

// ------- Kernel B: per-node MFMA gather: out[25,128] = x + W[25,K]@M[K,128] ---
__global__ __launch_bounds__(256, 4) void gather_mfma_kernel(
    const float* __restrict__ x,               // [N,25,128]
    const unsigned short* __restrict__ m0p,    // [(5E+pad)][128] bf16
    const unsigned short* __restrict__ wkT,    // [(5E+pad)][32] bf16
    const int* __restrict__ offs,
    float* __restrict__ out, int N)
{
    const int n  = blockIdx.x;
    const int t  = threadIdx.x;
    const int w  = t >> 6;
    const int l  = t & 63;
    const int ln = l & 15;
    const int q  = l >> 4;
    const int myk = 8 * q;

    const int beg = offs[n], end = offs[n + 1];
    const int K = 5 * (end - beg);
    const size_t beg5 = (size_t)5 * beg;
    const size_t obase = (size_t)n * (NCOEF * C_DIM);

    // prefetch x (completes under the GEMM)
    float xv[2][4][2];
    #pragma unroll
    for (int mt = 0; mt < 2; ++mt) {
        #pragma unroll
        for (int r = 0; r < 4; ++r) {
            const int i = mt * 16 + 4 * q + r;
            #pragma unroll
            for (int bt = 0; bt < 2; ++bt)
                xv[mt][r][bt] = (i < NCOEF)
                    ? x[obase + (size_t)i * C_DIM + 32 * w + bt * 16 + ln] : 0.0f;
        }
    }

    f32x4 acc[2][2];
    #pragma unroll
    for (int mt = 0; mt < 2; ++mt)
        #pragma unroll
        for (int bt = 0; bt < 2; ++bt)
            acc[mt][bt] = (f32x4){0.f, 0.f, 0.f, 0.f};

    const int nk = (K + 31) >> 5;

#define LOADF(KT, AF, BF) do {                                                  \
    const int kb_ = (KT) * 32;                                                  \
    const unsigned short* wrow_ = wkT + (beg5 + kb_ + myk) * 32 + ln;           \
    const unsigned short* mrow_ = m0p + (beg5 + kb_ + myk) * 128 + w * 32 + ln; \
    if (kb_ + 32 <= K) {                                                        \
        _Pragma("unroll")                                                       \
        for (int j = 0; j < 8; ++j) {                                           \
            AF[0][j] = (short)wrow_[j * 32];                                    \
            AF[1][j] = (short)wrow_[j * 32 + 16];                               \
            BF[0][j] = (short)mrow_[j * 128];                                   \
            BF[1][j] = (short)mrow_[j * 128 + 16];                              \
        }                                                                       \
    } else {                                                                    \
        const int limit_ = K - kb_;                                             \
        _Pragma("unroll")                                                       \
        for (int j = 0; j < 8; ++j) {                                           \
            const bool ok_ = (myk + j) < limit_;                                \
            AF[0][j] = ok_ ? (short)wrow_[j * 32] : (short)0;                   \
            AF[1][j] = ok_ ? (short)wrow_[j * 32 + 16] : (short)0;              \
            BF[0][j] = ok_ ? (short)mrow_[j * 128] : (short)0;                  \
            BF[1][j] = ok_ ? (short)mrow_[j * 128 + 16] : (short)0;             \
        }                                                                       \
    } } while (0)

#define MFMA4(AF, BF) do {                                                              \
    acc[0][0] = __builtin_amdgcn_mfma_f32_16x16x32_bf16(AF[0], BF[0], acc[0][0], 0,0,0);\
    acc[0][1] = __builtin_amdgcn_mfma_f32_16x16x32_bf16(AF[0], BF[1], acc[0][1], 0,0,0);\
    acc[1][0] = __builtin_amdgcn_mfma_f32_16x16x32_bf16(AF[1], BF[0], acc[1][0], 0,0,0);\
    acc[1][1] = __builtin_amdgcn_mfma_f32_16x16x32_bf16(AF[1], BF[1], acc[1][1], 0,0,0);\
    } while (0)

    short8 afA[2], bfA[2], afB[2], bfB[2];
    if (nk > 0) {
        LOADF(0, afA, bfA);
        int kt = 0;
        while (true) {
            if (kt + 1 < nk) LOADF(kt + 1, afB, bfB);
            MFMA4(afA, bfA);
            ++kt;
            if (kt >= nk) break;
            if (kt + 1 < nk) LOADF(kt + 1, afA, bfA);
            MFMA4(afB, bfB);
            ++kt;
            if (kt >= nk) break;
        }
    }
#undef LOADF
#undef MFMA4

    // epilogue: out = x + acc   (i = mt*16 + 4q + r, c = 32w + bt*16 + ln)
    #pragma unroll
    for (int mt = 0; mt < 2; ++mt) {
        #pragma unroll
        for (int r = 0; r < 4; ++r) {
            const int i = mt * 16 + 4 * q + r;
            if (i < NCOEF) {
                #pragma unroll
                for (int bt = 0; bt < 2; ++bt) {
                    const size_t idx = obase + (size_t)i * C_DIM + 32 * w + bt * 16 + ln;
                    out[idx] = xv[mt][r][bt] + acc[mt][bt][r];
                }
            }
        }
    }
}

// ---------------- Fallback (round-1 atomic version) ----------------
constexpr int FEB = 8;
constexpr int BT  = 256;

__device__ __forceinline__ float ln_silu(float v, float g, float be) {
    float s = v;
    #pragma unroll
    for (int o = 32; o; o >>= 1) s += __shfl_xor(s, o, 64);
    float mu = s * (1.0f / 64.0f);
    float dv = v - mu;
    float q  = dv * dv;
    #pragma unroll
    for (int o = 32; o; o >>= 1) q += __shfl_xor(q, o, 64);
    float rstd = rsqrtf(q * (1.0f / 64.0f) + EPS_LN);
    float z = dv * rstd * g + be;
    return z / (1.0f + __expf(-z));
}

__global__ __launch_bounds__(BT) void edge_degree_fallback(
    const float* __restrict__ x_edge, const float* __restrict__ edge_distance,
    const float* __restrict__ wigner_inv, const int* __restrict__ edge_index,
    const float* __restrict__ w1, const float* __restrict__ b1,
    const float* __restrict__ g1, const float* __restrict__ be1,
    const float* __restrict__ w2, const float* __restrict__ b2,
    const float* __restrict__ g2, const float* __restrict__ be2,
    const float* __restrict__ w3, const float* __restrict__ b3,
    const int* __restrict__ node_offset_p, float* __restrict__ out, int E)
{
    __shared__ float s_xe[FEB][C_DIM];
    __shared__ float s_h1[FEB][64];
    __shared__ float s_h2[FEB][64];
    __shared__ float s_wig[FEB][NCOEF * M0d];
    __shared__ float s_scale[FEB];
    __shared__ int   s_dst[FEB];

    const int t = threadIdx.x;
    const int g0 = blockIdx.x * FEB;
    const int ne = (E - g0) < FEB ? (E - g0) : FEB;

    {
        const float* src = x_edge + (size_t)g0 * C_DIM;
        for (int f = t; f < FEB * C_DIM; f += BT) {
            int e = f >> 7;
            ((float*)s_xe)[f] = (e < ne) ? src[f] : 0.0f;
        }
    }
    {
        const int wcol_[M0d] = {0, 2, 6, 12, 20};
        for (int f = t; f < FEB * NCOEF * M0d; f += BT) {
            int e = f / 125, r = f - e * 125, i = r / 5, a = r - i * 5;
            float v = 0.0f;
            if (e < ne)
                v = wigner_inv[((size_t)(g0 + e)) * (NCOEF * NCOEF) + i * NCOEF + wcol_[a]];
            s_wig[e][r] = v;
        }
    }
    if (t < FEB) {
        if (t < ne) {
            float d = edge_distance[g0 + t] * INV_CUTOFF;
            float d2 = d * d, d5 = d2 * d2 * d;
            float env = 1.0f + d5 * (-21.0f + d * (35.0f + d * (-15.0f)));
            s_scale[t] = ((d < 1.0f) ? env : 0.0f) * INV_RESCALE;
            s_dst[t] = edge_index[E + g0 + t] - node_offset_p[0];
        } else { s_scale[t] = 0.0f; s_dst[t] = 0; }
    }
    __syncthreads();

    const int wv = t >> 6, j = t & 63;
    {
        float acc0 = b1[j], acc1 = acc0;
        for (int k = 0; k < C_DIM; ++k) {
            float w = w1[k * 64 + j];
            acc0 += s_xe[wv][k] * w;
            acc1 += s_xe[wv + 4][k] * w;
        }
        const float g = g1[j], be = be1[j];
        s_h1[wv][j]     = ln_silu(acc0, g, be);
        s_h1[wv + 4][j] = ln_silu(acc1, g, be);
    }
    __syncthreads();
    {
        float acc0 = b2[j], acc1 = acc0;
        for (int k = 0; k < 64; ++k) {
            float w = w2[k * 64 + j];
            acc0 += s_h1[wv][k] * w;
            acc1 += s_h1[wv + 4][k] * w;
        }
        const float g = g2[j], be = be2[j];
        s_h2[wv][j]     = ln_silu(acc0, g, be);
        s_h2[wv + 4][j] = ln_silu(acc1, g, be);
    }
    __syncthreads();

    const int c = t & 127, half = t >> 7;
    float m0r[4][M0d];
    #pragma unroll
    for (int a = 0; a < M0d; ++a) {
        float bb = b3[a * C_DIM + c];
        float a0 = bb, a1 = bb, a2 = bb, a3 = bb;
        const float* w3c = w3 + a * C_DIM + c;
        for (int k = 0; k < 64; ++k) {
            float w = w3c[k * (M0d * C_DIM)];
            a0 += s_h2[half + 0][k] * w;
            a1 += s_h2[half + 2][k] * w;
            a2 += s_h2[half + 4][k] * w;
            a3 += s_h2[half + 6][k] * w;
        }
        m0r[0][a] = a0; m0r[1][a] = a1; m0r[2][a] = a2; m0r[3][a] = a3;
    }
    #pragma unroll
    for (int ei = 0; ei < 4; ++ei) {
        const int e = half + 2 * ei;
        if (e >= ne) continue;
        const float sc = s_scale[e];
        float* obase = out + (size_t)s_dst[e] * (NCOEF * C_DIM) + c;
        #pragma unroll
        for (int i = 0; i < NCOEF; ++i) {
            const float* wg = &s_wig[e][i * M0d];
            float v = wg[0] * m0r[ei][0] + wg[1] * m0r[ei][1] + wg[2] * m0r[ei][2]
                    + wg[3] * m0r[ei][3] + wg[4] * m0r[ei][4];
            atomicAdd(obase + i * C_DIM, v * sc);
        }
    }
}

extern "C" void kernel_launch(void* const* d_in, const int* in_sizes, int n_in,
                              void* d_out, int out_size, void* d_ws, size_t ws_size,
                              hipStream_t stream)
{
    const float* x             = (const float*)d_in[0];
    const float* x_edge        = (const float*)d_in[1];
    const float* edge_distance = (const float*)d_in[2];
    const float* wigner_inv    = (const float*)d_in[3];
    const int*   edge_index    = (const int*)d_in[4];
    const float* w1  = (const float*)d_in[5];
    const float* b1  = (const float*)d_in[6];
    const float* g1  = (const float*)d_in[7];
    const float* be1 = (const float*)d_in[8];
    const float* w2  = (const float*)d_in[9];
    const float* b2  = (const float*)d_in[10];
    const float* g2  = (const float*)d_in[11];
    const float* be2 = (const float*)d_in[12];
    const float* w3  = (const float*)d_in[13];
    const float* b3  = (const float*)d_in[14];
    const int*   node_offset = (const int*)d_in[15];

    float* out = (float*)d_out;
    const int E = in_sizes[1] / C_DIM;
    const int N = in_sizes[0] / (NCOEF * C_DIM);
    const size_t KROWS = (size_t)5 * E + 32;   // K rows + tail pad

    size_t off = 0;
    const size_t m0p_off  = off; off += KROWS * 128 * 2;   // bf16
    const size_t wkT_off  = off; off += KROWS * 32 * 2;    // bf16
    const size_t cnt_off  = off; off += (size_t)N * 4;
    const size_t cur_off  = off; off += (size_t)N * 4;
    const size_t offs_off = off; off += (size_t)(N + 1) * 4;
    off = (off + 255) & ~(size_t)255;
    const size_t w1T_off  = off; off += 64 * 128 * 2;
    const size_t w2T_off  = off; off += 64 * 64 * 2;
    const size_t w3T_off  = off; off += 640 * 64 * 2;
    const size_t need     = off;

    if (ws_size >= need) {
        char* ws   = (char*)d_ws;
        unsigned short* m0p = (unsigned short*)(ws + m0p_off);
        unsigned short* wkT = (unsigned short*)(ws + wkT_off);
        int* cnt   = (int*)(ws + cnt_off);
        int* cur   = (int*)(ws + cur_off);
        int* offs  = (int*)(ws + offs_off);
        short* w1T = (short*)(ws + w1T_off);
        short* w2T = (short*)(ws + w2T_off);
        short* w3T = (short*)(ws + w3T_off);

        const int prepN = (640 * 64 > 2 * N) ? 640 * 64 : 2 * N;
        prep_kernel<<<(prepN + 255) / 256, 256, 0, stream>>>(
            w1, w2, w3, w1T, w2T, w3T, cnt, 2 * N);
        count_kernel<<<(E + 255) / 256, 256, 0, stream>>>(edge_index, node_offset, cnt, E, N);
        scan_kernel<<<1, 256, 0, stream>>>(cnt, offs, N);

        const int nChunk = (E + 15) / 16;
        mlp_mfma_kernel<<<(nChunk + MCH - 1) / MCH, 256, 0, stream>>>(
            x_edge, edge_distance, wigner_inv, edge_index, node_offset, offs, cur,
            w1T, b1, g1, be1, w2T, b2, g2, be2, w3T, b3, m0p, wkT, E, N, nChunk);

        gather_mfma_kernel<<<N, 256, 0, stream>>>(x, m0p, wkT, offs, out, N);
    } else {
        hipMemcpyAsync(out, x, (size_t)out_size * sizeof(float),
                       hipMemcpyDeviceToDevice, stream);
        edge_degree_fallback<<<(E + FEB - 1) / FEB, BT, 0, stream>>>(
            x_edge, edge_distance, wigner_inv, edge_index,
            w1, b1, g1, be1, w2, b2, g2, be2, w3, b3,
            node_offset, out, E);
    }
}

// Round 20
// 112.967 us; speedup vs baseline: 1.3069x; 1.3069x over previous
//
#include <hip/hip_runtime.h>
#include <cstddef>

// EdgeDegreeEmbedding fused pipeline for MI355X (gfx950)
//
//   h1 = silu(LN(x_edge @ w1 + b1))          [E,64]
//   h2 = silu(LN(h1 @ w2 + b2))              [E,64]
//   m0 = (h2 @ w3 + b3) * env(d/12)/5        -> m0p perm-K-major bf16
//   out[dst[e]] += W-contraction              (per-node MFMA GEMM, K=5*cnt)
//   out initialized to x.
//
// Round-20: REVERT to r18 (113.4us best). r19's in-kernel compact phase
// evicted the persistent weights (VGPR capped at 128, 72MB spill traffic)
// — same failure mode as r16. The persistent-weight mlp has no VGPR
// headroom for extra phases; keep compact as its own kernel.

constexpr int C_DIM   = 128;
constexpr int NCOEF   = 25;
constexpr int M0d     = 5;
constexpr int MCH     = 5;     // 16-edge chunks per mlp block
constexpr float EPS_LN      = 1e-5f;
constexpr float INV_CUTOFF  = 1.0f / 12.0f;
constexpr float INV_RESCALE = 0.2f;

typedef __attribute__((ext_vector_type(8))) short short8;   // 8 bf16
typedef __attribute__((ext_vector_type(4))) short short4v;  // 4 bf16
typedef __attribute__((ext_vector_type(4))) float f32x4;

__device__ __forceinline__ short f2bf(float f) {
    unsigned u = __float_as_uint(f);
    unsigned r = u + 0x7FFFu + ((u >> 16) & 1u);   // round-to-nearest-even
    return (short)(r >> 16);
}

__device__ __forceinline__ float silu(float z) {
    return z / (1.0f + __expf(-z));
}

// -------- Kernel P: zero bins + weights -> bf16 transposed (one launch) -------
__global__ __launch_bounds__(256) void prep_kernel(
    const float* __restrict__ w1, const float* __restrict__ w2,
    const float* __restrict__ w3,
    short* __restrict__ w1T, short* __restrict__ w2T, short* __restrict__ w3T,
    int* __restrict__ cnt, int n2)
{
    int i = blockIdx.x * 256 + threadIdx.x;
    if (i < n2) cnt[i] = 0;
    if (i < 64 * 128) {             // w1T[n*128+k] = w1[k*64+n]
        int n = i >> 7, k = i & 127;
        w1T[i] = f2bf(w1[k * 64 + n]);
    }
    if (i < 64 * 64) {              // w2T[n*64+k] = w2[k*64+n]
        int n = i >> 6, k = i & 63;
        w2T[i] = f2bf(w2[k * 64 + n]);
    }
    if (i < 640 * 64) {             // w3T[n*64+k] = w3[k*640+n]
        int n = i >> 6, k = i & 63;
        w3T[i] = f2bf(w3[k * 640 + n]);
    }
}

// ---------------- Binning ----------------
__global__ __launch_bounds__(256) void count_kernel(
    const int* __restrict__ edge_index, const int* __restrict__ noff,
    int* __restrict__ cnt, int E, int N)
{
    int e = blockIdx.x * 256 + threadIdx.x;
    if (e < E) {
        int d = edge_index[E + e] - noff[0];
        if (d >= 0 && d < N) atomicAdd(&cnt[d], 1);
    }
}

__global__ __launch_bounds__(256) void scan_kernel(
    const int* __restrict__ cnt, int* __restrict__ offs, int N)
{
    __shared__ int s_wsum[4];
    const int t = threadIdx.x;
    const int lane = t & 63, w = t >> 6;
    const int chunk = (N + 255) / 256;
    const int base = t * chunk;

    int s = 0;
    for (int j = 0; j < chunk; ++j)
        if (base + j < N) s += cnt[base + j];

    int v = s;
    #pragma unroll
    for (int off = 1; off < 64; off <<= 1) {
        int u = __shfl_up(v, off, 64);
        if (lane >= off) v += u;
    }
    if (lane == 63) s_wsum[w] = v;
    __syncthreads();
    int wbase = 0;
    for (int k = 0; k < w; ++k) wbase += s_wsum[k];
    int run = wbase + v - s;

    if (t == 0) offs[0] = 0;
    for (int j = 0; j < chunk; ++j) {
        if (base + j < N) {
            run += cnt[base + j];
            offs[base + j + 1] = run;
        }
    }
}

// ---- Kernel C: assign ipos (merged fill) + stream wigner -> wkT K-major ----
__global__ __launch_bounds__(256) void compact_kernel(
    const float* __restrict__ wigner_inv,  // [E,625]
    const int*   __restrict__ edge_index,  // [2,E]
    const int*   __restrict__ noff,
    const int*   __restrict__ offs,        // [N+1]
    int*         __restrict__ cur,         // [N]
    int*         __restrict__ ipos,        // [E] out
    unsigned short* __restrict__ wkT,      // [(5E+pad)][32] bf16
    int E, int N)
{
    __shared__ float s_raw[16 * 625];      // 40 KB
    __shared__ int   s_ipos[16];

    const int t  = threadIdx.x;
    const int g0 = blockIdx.x * 16;
    const int nloc = (E - g0) < 16 ? (E - g0) : 16;

    if (t < nloc) {
        const int e = g0 + t;
        const int d = edge_index[E + e] - noff[0];
        int ip = -1;
        if (d >= 0 && d < N) {
            int p = atomicAdd(&cur[d], 1);
            ip = offs[d] + p;
        }
        s_ipos[t] = ip;
        ipos[e]   = ip;
    }

    if (nloc == 16) {
        const float4* src = (const float4*)(wigner_inv + (size_t)g0 * 625);
        #pragma unroll 4
        for (int f = t; f < 2500; f += 256)
            *(float4*)&s_raw[f * 4] = src[f];
    } else {
        const float* src = wigner_inv + (size_t)g0 * 625;
        for (int f = t; f < nloc * 625; f += 256)
            s_raw[f] = src[f];
    }
    __syncthreads();

    const int total = nloc * 160;   // 5 a * 32 i per edge
    #pragma unroll 4
    for (int f = t; f < total; f += 256) {
        int el = f / 160;
        int r  = f - el * 160;
        int a  = r >> 5;
        int i  = r & 31;
        int ip = s_ipos[el];
        if ((unsigned)ip < (unsigned)E) {
            unsigned short v = 0;
            if (i < 25) v = (unsigned short)f2bf(s_raw[el * 625 + i * 25 + a * (a + 1)]);
            wkT[((size_t)ip * 5 + a) * 32 + i] = v;
        }
    }
}

// ------- Kernel A: MFMA radial MLP (persistent weights) -> m0p ----------
// Each block: MCH chunks of 16 edges. Wave w holds channel-tile w of
// w1/w2 and tiles w*10..w*10+9 of w3 + all biases in registers.
// LayerNorm uses single-barrier sum+sumsq reduction (var = E[x^2]-mu^2).
__global__ __launch_bounds__(256, 2) void mlp_mfma_kernel(
    const float* __restrict__ x_edge,        // [E,128]
    const float* __restrict__ edge_distance, // [E]
    const int*   __restrict__ ipos,          // [E]
    const short* __restrict__ w1T,           // [64][128] bf16
    const float* __restrict__ b1,
    const float* __restrict__ g1, const float* __restrict__ be1,
    const short* __restrict__ w2T,           // [64][64] bf16
    const float* __restrict__ b2,
    const float* __restrict__ g2, const float* __restrict__ be2,
    const short* __restrict__ w3T,           // [640][64] bf16
    const float* __restrict__ b3,
    unsigned short* __restrict__ m0p,        // [(5E+pad)][128] bf16, perm order
    int E, int nChunk)
{
    __shared__ float s_part[128];             // LN partials: [0:64) sum, [64:128) sumsq
    __shared__ short sh1[1024];               // 16x64 bf16, swizzled
    __shared__ short sh2[1024];

    const int t   = threadIdx.x;
    const int w   = t >> 6;
    const int l   = t & 63;
    const int e16 = l & 15;
    const int g   = l >> 4;
    const int swz = (e16 & 7) << 4;

    char* sh1b = (char*)sh1;
    char* sh2b = (char*)sh2;

    // ---- persistent weights & biases (loaded once per block) ----
    short8 aw1[4], aw2[2], aw3a[10], aw3b[10];
    #pragma unroll
    for (int kt = 0; kt < 4; ++kt)
        aw1[kt] = *(const short8*)(w1T + (w * 16 + e16) * 128 + kt * 32 + 8 * g);
    #pragma unroll
    for (int kt = 0; kt < 2; ++kt)
        aw2[kt] = *(const short8*)(w2T + (w * 16 + e16) * 64 + kt * 32 + 8 * g);
    #pragma unroll
    for (int j = 0; j < 10; ++j) {
        const int nt = w * 10 + j;
        aw3a[j] = *(const short8*)(w3T + (nt * 16 + e16) * 64 + 8 * g);
        aw3b[j] = *(const short8*)(w3T + (nt * 16 + e16) * 64 + 32 + 8 * g);
    }
    const float4 b1v  = *(const float4*)(b1  + w * 16 + 4 * g);
    const float4 g1v  = *(const float4*)(g1  + w * 16 + 4 * g);
    const float4 be1v = *(const float4*)(be1 + w * 16 + 4 * g);
    const float4 b2v  = *(const float4*)(b2  + w * 16 + 4 * g);
    const float4 g2v  = *(const float4*)(g2  + w * 16 + 4 * g);
    const float4 be2v = *(const float4*)(be2 + w * 16 + 4 * g);
    float4 b3v[10];
    #pragma unroll
    for (int j = 0; j < 10; ++j)
        b3v[j] = *(const float4*)(b3 + (w * 10 + j) * 16 + 4 * g);

    const int ch0 = (int)blockIdx.x * MCH;
    const int chE = (ch0 + MCH < nChunk) ? (ch0 + MCH) : nChunk;

    for (int ch = ch0; ch < chE; ++ch) {
        const int g0  = ch * 16;
        const int row = g0 + e16;
        const int rowc = row < E ? row : (E - 1);
        const bool valid = row < E;

        float sc;
        {
            float d  = edge_distance[rowc] * INV_CUTOFF;
            float d2 = d * d;
            float d5 = d2 * d2 * d;
            float env = 1.0f + d5 * (-21.0f + d * (35.0f + d * (-15.0f)));
            sc = ((d < 1.0f) ? env : 0.0f) * INV_RESCALE;
        }
        const int ip = valid ? ipos[rowc] : -1;
        const bool ipok = valid && ((unsigned)ip < (unsigned)E);

        // B1 fragments from x_edge
        short8 bx[4];
        {
            const float* xr = x_edge + (size_t)rowc * C_DIM + 8 * g;
            #pragma unroll
            for (int kt = 0; kt < 4; ++kt) {
                float4 f0 = *(const float4*)(xr + kt * 32);
                float4 f1 = *(const float4*)(xr + kt * 32 + 4);
                short8 v;
                v[0] = f2bf(f0.x); v[1] = f2bf(f0.y); v[2] = f2bf(f0.z); v[3] = f2bf(f0.w);
                v[4] = f2bf(f1.x); v[5] = f2bf(f1.y); v[6] = f2bf(f1.z); v[7] = f2bf(f1.w);
                bx[kt] = v;
            }
        }

        // Layer 1
        f32x4 acc1 = {b1v.x, b1v.y, b1v.z, b1v.w};
        #pragma unroll
        for (int kt = 0; kt < 4; ++kt)
            acc1 = __builtin_amdgcn_mfma_f32_16x16x32_bf16(aw1[kt], bx[kt], acc1, 0, 0, 0);

        // LN1 (single-barrier: sum + sumsq) + SiLU -> sh1
        {
            float s = acc1[0] + acc1[1] + acc1[2] + acc1[3];
            float qq = acc1[0]*acc1[0] + acc1[1]*acc1[1] + acc1[2]*acc1[2] + acc1[3]*acc1[3];
            s  += __shfl_xor(s, 16);  s  += __shfl_xor(s, 32);
            qq += __shfl_xor(qq, 16); qq += __shfl_xor(qq, 32);
            if (g == 0) { s_part[w * 16 + e16] = s; s_part[64 + w * 16 + e16] = qq; }
            __syncthreads();
            float mu  = (s_part[e16] + s_part[16 + e16] + s_part[32 + e16] + s_part[48 + e16])
                        * (1.0f / 64.0f);
            float ex2 = (s_part[64 + e16] + s_part[80 + e16] + s_part[96 + e16] + s_part[112 + e16])
                        * (1.0f / 64.0f);
            float var = ex2 - mu * mu;
            float rstd = rsqrtf((var > 0.0f ? var : 0.0f) + EPS_LN);
            short4v hv;
            hv[0] = f2bf(silu((acc1[0] - mu) * rstd * g1v.x + be1v.x));
            hv[1] = f2bf(silu((acc1[1] - mu) * rstd * g1v.y + be1v.y));
            hv[2] = f2bf(silu((acc1[2] - mu) * rstd * g1v.z + be1v.z));
            hv[3] = f2bf(silu((acc1[3] - mu) * rstd * g1v.w + be1v.w));
            __syncthreads();   // ensure all reads of s_part done before reuse / sh1 write order
            *(short4v*)(sh1b + e16 * 128 + ((w * 32 + 8 * g) ^ swz)) = hv;
            __syncthreads();
        }

        // Layer 2
        f32x4 acc2 = {b2v.x, b2v.y, b2v.z, b2v.w};
        {
            short8 bh[2];
            #pragma unroll
            for (int kt = 0; kt < 2; ++kt)
                bh[kt] = *(const short8*)(sh1b + e16 * 128 + ((kt * 64 + 16 * g) ^ swz));
            #pragma unroll
            for (int kt = 0; kt < 2; ++kt)
                acc2 = __builtin_amdgcn_mfma_f32_16x16x32_bf16(aw2[kt], bh[kt], acc2, 0, 0, 0);
        }

        // LN2 (single-barrier) + SiLU -> sh2
        {
            float s = acc2[0] + acc2[1] + acc2[2] + acc2[3];
            float qq = acc2[0]*acc2[0] + acc2[1]*acc2[1] + acc2[2]*acc2[2] + acc2[3]*acc2[3];
            s  += __shfl_xor(s, 16);  s  += __shfl_xor(s, 32);
            qq += __shfl_xor(qq, 16); qq += __shfl_xor(qq, 32);
            if (g == 0) { s_part[w * 16 + e16] = s; s_part[64 + w * 16 + e16] = qq; }
            __syncthreads();
            float mu  = (s_part[e16] + s_part[16 + e16] + s_part[32 + e16] + s_part[48 + e16])
                        * (1.0f / 64.0f);
            float ex2 = (s_part[64 + e16] + s_part[80 + e16] + s_part[96 + e16] + s_part[112 + e16])
                        * (1.0f / 64.0f);
            float var = ex2 - mu * mu;
            float rstd = rsqrtf((var > 0.0f ? var : 0.0f) + EPS_LN);
            short4v hv;
            hv[0] = f2bf(silu((acc2[0] - mu) * rstd * g2v.x + be2v.x));
            hv[1] = f2bf(silu((acc2[1] - mu) * rstd * g2v.y + be2v.y));
            hv[2] = f2bf(silu((acc2[2] - mu) * rstd * g2v.z + be2v.z));
            hv[3] = f2bf(silu((acc2[3] - mu) * rstd * g2v.w + be2v.w));
            __syncthreads();
            *(short4v*)(sh2b + e16 * 128 + ((w * 32 + 8 * g) ^ swz)) = hv;
            __syncthreads();
        }

        // Layer 3: 10 tiles/wave from persistent regs, perm-ordered stores
        {
            short8 bh2[2];
            #pragma unroll
            for (int kt = 0; kt < 2; ++kt)
                bh2[kt] = *(const short8*)(sh2b + e16 * 128 + ((kt * 64 + 16 * g) ^ swz));

            #pragma unroll
            for (int j = 0; j < 10; ++j) {
                const int nt = w * 10 + j;
                f32x4 a3 = {b3v[j].x, b3v[j].y, b3v[j].z, b3v[j].w};
                a3 = __builtin_amdgcn_mfma_f32_16x16x32_bf16(aw3a[j], bh2[0], a3, 0, 0, 0);
                a3 = __builtin_amdgcn_mfma_f32_16x16x32_bf16(aw3b[j], bh2[1], a3, 0, 0, 0);
                if (ipok) {
                    short4v o;
                    o[0] = f2bf(a3[0] * sc);
                    o[1] = f2bf(a3[1] * sc);
                    o[2] = f2bf(a3[2] * sc);
                    o[3] = f2bf(a3[3] * sc);
                    *(short4v*)(m0p + ((size_t)ip * 5 + (nt >> 3)) * 128
                                    + ((nt & 7) << 4) + 4 * g) = o;
                }
            }
        }
        __syncthreads();   // protect sh1/sh2/s_part reuse across chunks
    }
}

// ------- Kernel B: per-node MFMA gather: out[25,128] = x + W[25,K]@M[K,128] ---
// 4 independent waves/block, no LDS. 2-stage software pipeline on K-tiles;
// unmasked fast path for fully-in-range tiles; x prefetched before K-loop.
__global__ __launch_bounds__(256, 4) void gather_mfma_kernel(
    const float* __restrict__ x,               // [N,25,128]
    const unsigned short* __restrict__ m0p,    // [(5E+pad)][128] bf16
    const unsigned short* __restrict__ wkT,    // [(5E+pad)][32] bf16
    const int* __restrict__ offs,
    float* __restrict__ out, int N)
{
    const int n  = blockIdx.x;
    const int t  = threadIdx.x;
    const int w  = t >> 6;
    const int l  = t & 63;
    const int ln = l & 15;
    const int q  = l >> 4;
    const int myk = 8 * q;

    const int beg = offs[n], end = offs[n + 1];
    const int K = 5 * (end - beg);
    const size_t beg5 = (size_t)5 * beg;
    const size_t obase = (size_t)n * (NCOEF * C_DIM);

    // prefetch x (completes under the GEMM)
    float xv[2][4][2];
    #pragma unroll
    for (int mt = 0; mt < 2; ++mt) {
        #pragma unroll
        for (int r = 0; r < 4; ++r) {
            const int i = mt * 16 + 4 * q + r;
            #pragma unroll
            for (int bt = 0; bt < 2; ++bt)
                xv[mt][r][bt] = (i < NCOEF)
                    ? x[obase + (size_t)i * C_DIM + 32 * w + bt * 16 + ln] : 0.0f;
        }
    }

    f32x4 acc[2][2];
    #pragma unroll
    for (int mt = 0; mt < 2; ++mt)
        #pragma unroll
        for (int bt = 0; bt < 2; ++bt)
            acc[mt][bt] = (f32x4){0.f, 0.f, 0.f, 0.f};

    const int nk = (K + 31) >> 5;

#define LOADF(KT, AF, BF) do {                                                  \
    const int kb_ = (KT) * 32;                                                  \
    const unsigned short* wrow_ = wkT + (beg5 + kb_ + myk) * 32 + ln;           \
    const unsigned short* mrow_ = m0p + (beg5 + kb_ + myk) * 128 + w * 32 + ln; \
    if (kb_ + 32 <= K) {                                                        \
        _Pragma("unroll")                                                       \
        for (int j = 0; j < 8; ++j) {                                           \
            AF[0][j] = (short)wrow_[j * 32];                                    \
            AF[1][j] = (short)wrow_[j * 32 + 16];                               \
            BF[0][j] = (short)mrow_[j * 128];                                   \
            BF[1][j] = (short)mrow_[j * 128 + 16];                              \
        }                                                                       \
    } else {                                                                    \
        const int limit_ = K - kb_;                                             \
        _Pragma("unroll")                                                       \
        for (int j = 0; j < 8; ++j) {                                           \
            const bool ok_ = (myk + j) < limit_;                                \
            AF[0][j] = ok_ ? (short)wrow_[j * 32] : (short)0;                   \
            AF[1][j] = ok_ ? (short)wrow_[j * 32 + 16] : (short)0;              \
            BF[0][j] = ok_ ? (short)mrow_[j * 128] : (short)0;                  \
            BF[1][j] = ok_ ? (short)mrow_[j * 128 + 16] : (short)0;             \
        }                                                                       \
    } } while (0)

#define MFMA4(AF, BF) do {                                                              \
    acc[0][0] = __builtin_amdgcn_mfma_f32_16x16x32_bf16(AF[0], BF[0], acc[0][0], 0,0,0);\
    acc[0][1] = __builtin_amdgcn_mfma_f32_16x16x32_bf16(AF[0], BF[1], acc[0][1], 0,0,0);\
    acc[1][0] = __builtin_amdgcn_mfma_f32_16x16x32_bf16(AF[1], BF[0], acc[1][0], 0,0,0);\
    acc[1][1] = __builtin_amdgcn_mfma_f32_16x16x32_bf16(AF[1], BF[1], acc[1][1], 0,0,0);\
    } while (0)

    short8 afA[2], bfA[2], afB[2], bfB[2];
    if (nk > 0) {
        LOADF(0, afA, bfA);
        int kt = 0;
        while (true) {
            if (kt + 1 < nk) LOADF(kt + 1, afB, bfB);
            MFMA4(afA, bfA);
            ++kt;
            if (kt >= nk) break;
            if (kt + 1 < nk) LOADF(kt + 1, afA, bfA);
            MFMA4(afB, bfB);
            ++kt;
            if (kt >= nk) break;
        }
    }
#undef LOADF
#undef MFMA4

    // epilogue: out = x + acc   (i = mt*16 + 4q + r, c = 32w + bt*16 + ln)
    #pragma unroll
    for (int mt = 0; mt < 2; ++mt) {
        #pragma unroll
        for (int r = 0; r < 4; ++r) {
            const int i = mt * 16 + 4 * q + r;
            if (i < NCOEF) {
                #pragma unroll
                for (int bt = 0; bt < 2; ++bt) {
                    const size_t idx = obase + (size_t)i * C_DIM + 32 * w + bt * 16 + ln;
                    out[idx] = xv[mt][r][bt] + acc[mt][bt][r];
                }
            }
        }
    }
}

// ---------------- Fallback (round-1 atomic version) ----------------
constexpr int FEB = 8;
constexpr int BT  = 256;

__device__ __forceinline__ float ln_silu(float v, float g, float be) {
    float s = v;
    #pragma unroll
    for (int o = 32; o; o >>= 1) s += __shfl_xor(s, o, 64);
    float mu = s * (1.0f / 64.0f);
    float dv = v - mu;
    float q  = dv * dv;
    #pragma unroll
    for (int o = 32; o; o >>= 1) q += __shfl_xor(q, o, 64);
    float rstd = rsqrtf(q * (1.0f / 64.0f) + EPS_LN);
    float z = dv * rstd * g + be;
    return z / (1.0f + __expf(-z));
}

__global__ __launch_bounds__(BT) void edge_degree_fallback(
    const float* __restrict__ x_edge, const float* __restrict__ edge_distance,
    const float* __restrict__ wigner_inv, const int* __restrict__ edge_index,
    const float* __restrict__ w1, const float* __restrict__ b1,
    const float* __restrict__ g1, const float* __restrict__ be1,
    const float* __restrict__ w2, const float* __restrict__ b2,
    const float* __restrict__ g2, const float* __restrict__ be2,
    const float* __restrict__ w3, const float* __restrict__ b3,
    const int* __restrict__ node_offset_p, float* __restrict__ out, int E)
{
    __shared__ float s_xe[FEB][C_DIM];
    __shared__ float s_h1[FEB][64];
    __shared__ float s_h2[FEB][64];
    __shared__ float s_wig[FEB][NCOEF * M0d];
    __shared__ float s_scale[FEB];
    __shared__ int   s_dst[FEB];

    const int t = threadIdx.x;
    const int g0 = blockIdx.x * FEB;
    const int ne = (E - g0) < FEB ? (E - g0) : FEB;

    {
        const float* src = x_edge + (size_t)g0 * C_DIM;
        for (int f = t; f < FEB * C_DIM; f += BT) {
            int e = f >> 7;
            ((float*)s_xe)[f] = (e < ne) ? src[f] : 0.0f;
        }
    }
    {
        const int wcol_[M0d] = {0, 2, 6, 12, 20};
        for (int f = t; f < FEB * NCOEF * M0d; f += BT) {
            int e = f / 125, r = f - e * 125, i = r / 5, a = r - i * 5;
            float v = 0.0f;
            if (e < ne)
                v = wigner_inv[((size_t)(g0 + e)) * (NCOEF * NCOEF) + i * NCOEF + wcol_[a]];
            s_wig[e][r] = v;
        }
    }
    if (t < FEB) {
        if (t < ne) {
            float d = edge_distance[g0 + t] * INV_CUTOFF;
            float d2 = d * d, d5 = d2 * d2 * d;
            float env = 1.0f + d5 * (-21.0f + d * (35.0f + d * (-15.0f)));
            s_scale[t] = ((d < 1.0f) ? env : 0.0f) * INV_RESCALE;
            s_dst[t] = edge_index[E + g0 + t] - node_offset_p[0];
        } else { s_scale[t] = 0.0f; s_dst[t] = 0; }
    }
    __syncthreads();

    const int wv = t >> 6, j = t & 63;
    {
        float acc0 = b1[j], acc1 = acc0;
        for (int k = 0; k < C_DIM; ++k) {
            float w = w1[k * 64 + j];
            acc0 += s_xe[wv][k] * w;
            acc1 += s_xe[wv + 4][k] * w;
        }
        const float g = g1[j], be = be1[j];
        s_h1[wv][j]     = ln_silu(acc0, g, be);
        s_h1[wv + 4][j] = ln_silu(acc1, g, be);
    }
    __syncthreads();
    {
        float acc0 = b2[j], acc1 = acc0;
        for (int k = 0; k < 64; ++k) {
            float w = w2[k * 64 + j];
            acc0 += s_h1[wv][k] * w;
            acc1 += s_h1[wv + 4][k] * w;
        }
        const float g = g2[j], be = be2[j];
        s_h2[wv][j]     = ln_silu(acc0, g, be);
        s_h2[wv + 4][j] = ln_silu(acc1, g, be);
    }
    __syncthreads();

    const int c = t & 127, half = t >> 7;
    float m0r[4][M0d];
    #pragma unroll
    for (int a = 0; a < M0d; ++a) {
        float bb = b3[a * C_DIM + c];
        float a0 = bb, a1 = bb, a2 = bb, a3 = bb;
        const float* w3c = w3 + a * C_DIM + c;
        for (int k = 0; k < 64; ++k) {
            float w = w3c[k * (M0d * C_DIM)];
            a0 += s_h2[half + 0][k] * w;
            a1 += s_h2[half + 2][k] * w;
            a2 += s_h2[half + 4][k] * w;
            a3 += s_h2[half + 6][k] * w;
        }
        m0r[0][a] = a0; m0r[1][a] = a1; m0r[2][a] = a2; m0r[3][a] = a3;
    }
    #pragma unroll
    for (int ei = 0; ei < 4; ++ei) {
        const int e = half + 2 * ei;
        if (e >= ne) continue;
        const float sc = s_scale[e];
        float* obase = out + (size_t)s_dst[e] * (NCOEF * C_DIM) + c;
        #pragma unroll
        for (int i = 0; i < NCOEF; ++i) {
            const float* wg = &s_wig[e][i * M0d];
            float v = wg[0] * m0r[ei][0] + wg[1] * m0r[ei][1] + wg[2] * m0r[ei][2]
                    + wg[3] * m0r[ei][3] + wg[4] * m0r[ei][4];
            atomicAdd(obase + i * C_DIM, v * sc);
        }
    }
}

extern "C" void kernel_launch(void* const* d_in, const int* in_sizes, int n_in,
                              void* d_out, int out_size, void* d_ws, size_t ws_size,
                              hipStream_t stream)
{
    const float* x             = (const float*)d_in[0];
    const float* x_edge        = (const float*)d_in[1];
    const float* edge_distance = (const float*)d_in[2];
    const float* wigner_inv    = (const float*)d_in[3];
    const int*   edge_index    = (const int*)d_in[4];
    const float* w1  = (const float*)d_in[5];
    const float* b1  = (const float*)d_in[6];
    const float* g1  = (const float*)d_in[7];
    const float* be1 = (const float*)d_in[8];
    const float* w2  = (const float*)d_in[9];
    const float* b2  = (const float*)d_in[10];
    const float* g2  = (const float*)d_in[11];
    const float* be2 = (const float*)d_in[12];
    const float* w3  = (const float*)d_in[13];
    const float* b3  = (const float*)d_in[14];
    const int*   node_offset = (const int*)d_in[15];

    float* out = (float*)d_out;
    const int E = in_sizes[1] / C_DIM;
    const int N = in_sizes[0] / (NCOEF * C_DIM);
    const size_t KROWS = (size_t)5 * E + 32;   // K rows + tail pad

    size_t off = 0;
    const size_t m0p_off  = off; off += KROWS * 128 * 2;   // bf16
    const size_t wkT_off  = off; off += KROWS * 32 * 2;    // bf16
    const size_t cnt_off  = off; off += (size_t)N * 4;
    const size_t cur_off  = off; off += (size_t)N * 4;
    const size_t offs_off = off; off += (size_t)(N + 1) * 4;
    const size_t ipos_off = off; off += (size_t)E * 4;
    off = (off + 255) & ~(size_t)255;
    const size_t w1T_off  = off; off += 64 * 128 * 2;
    const size_t w2T_off  = off; off += 64 * 64 * 2;
    const size_t w3T_off  = off; off += 640 * 64 * 2;
    const size_t need     = off;

    if (ws_size >= need) {
        char* ws   = (char*)d_ws;
        unsigned short* m0p = (unsigned short*)(ws + m0p_off);
        unsigned short* wkT = (unsigned short*)(ws + wkT_off);
        int* cnt   = (int*)(ws + cnt_off);
        int* cur   = (int*)(ws + cur_off);
        int* offs  = (int*)(ws + offs_off);
        int* ipos  = (int*)(ws + ipos_off);
        short* w1T = (short*)(ws + w1T_off);
        short* w2T = (short*)(ws + w2T_off);
        short* w3T = (short*)(ws + w3T_off);

        const int prepN = (640 * 64 > 2 * N) ? 640 * 64 : 2 * N;
        prep_kernel<<<(prepN + 255) / 256, 256, 0, stream>>>(
            w1, w2, w3, w1T, w2T, w3T, cnt, 2 * N);
        count_kernel<<<(E + 255) / 256, 256, 0, stream>>>(edge_index, node_offset, cnt, E, N);
        scan_kernel<<<1, 256, 0, stream>>>(cnt, offs, N);

        compact_kernel<<<(E + 15) / 16, 256, 0, stream>>>(
            wigner_inv, edge_index, node_offset, offs, cur, ipos, wkT, E, N);

        const int nChunk = (E + 15) / 16;
        mlp_mfma_kernel<<<(nChunk + MCH - 1) / MCH, 256, 0, stream>>>(
            x_edge, edge_distance, ipos,
            w1T, b1, g1, be1, w2T, b2, g2, be2, w3T, b3, m0p, E, nChunk);

        gather_mfma_kernel<<<N, 256, 0, stream>>>(x, m0p, wkT, offs, out, N);
    } else {
        hipMemcpyAsync(out, x, (size_t)out_size * sizeof(float),
                       hipMemcpyDeviceToDevice, stream);
        edge_degree_fallback<<<(E + FEB - 1) / FEB, BT, 0, stream>>>(
            x_edge, edge_distance, wigner_inv, edge_index,
            w1, b1, g1, be1, w2, b2, g2, be2, w3, b3,
            node_offset, out, E);
    }
}